// Round 1
// baseline (1946.654 us; speedup 1.0000x reference)
//
#include <hip/hip_runtime.h>

#define HD 64
#define SEQ 2304

union F4 { float4 v; float f[4]; };

// ---------------- QKV GEMM: [4608x768] @ [768x2304] + bias -> q,k,v [24][2304][64]
__global__ __launch_bounds__(256) void qkv_gemm_k(
    const float* __restrict__ x, const float* __restrict__ w,
    const float* __restrict__ bias,
    float* __restrict__ q, float* __restrict__ kk, float* __restrict__ vv)
{
  __shared__ float As[16][68];
  __shared__ float Bs[16][68];
  const int tid = threadIdx.x;
  const int tn = tid & 15, tm = tid >> 4;
  const int c0 = blockIdx.x * 64;   // 36 blocks
  const int r0 = blockIdx.y * 64;   // 72 blocks
  const int arow = tid >> 2, ak4 = (tid & 3) * 4;
  const int brow = tid >> 4, bc4 = (tid & 15) * 4;
  float acc[4][4] = {};
  const float* ap = x + (size_t)(r0 + arow) * 768 + ak4;
  const float* bp = w + (size_t)brow * 2304 + c0 + bc4;
  for (int k0 = 0; k0 < 768; k0 += 16) {
    F4 a4, b4;
    a4.v = *(const float4*)(ap + k0);
    b4.v = *(const float4*)(bp + (size_t)k0 * 2304);
    __syncthreads();
    As[ak4+0][arow] = a4.f[0];
    As[ak4+1][arow] = a4.f[1];
    As[ak4+2][arow] = a4.f[2];
    As[ak4+3][arow] = a4.f[3];
    *(float4*)&Bs[brow][bc4] = b4.v;
    __syncthreads();
#pragma unroll
    for (int p = 0; p < 16; p++) {
      F4 av, bv;
      av.v = *(float4*)&As[p][tm*4];
      bv.v = *(float4*)&Bs[p][tn*4];
#pragma unroll
      for (int i = 0; i < 4; i++)
#pragma unroll
        for (int j = 0; j < 4; j++)
          acc[i][j] += av.f[i] * bv.f[j];
    }
  }
  const int hg = blockIdx.x;            // = c0/64, 0..35
  const int which = hg / 12, head = hg % 12;
  const int b = r0 / 2304;
  float* dst = which == 0 ? q : (which == 1 ? kk : vv);
  float bb[4];
#pragma unroll
  for (int j = 0; j < 4; j++) bb[j] = bias[c0 + tn*4 + j];
#pragma unroll
  for (int i = 0; i < 4; i++) {
    int row = r0 + tm*4 + i;
    int s = row - b * 2304;
    F4 ov;
#pragma unroll
    for (int j = 0; j < 4; j++) ov.f[j] = acc[i][j] + bb[j];
    *(float4*)(dst + ((size_t)(b*12 + head) * SEQ + s) * 64 + tn*4) = ov.v;
  }
}

// ---------------- Fused attention with decomposed rel-pos bias, online softmax
__global__ __launch_bounds__(256) void attn_k(
    const float* __restrict__ q, const float* __restrict__ k,
    const float* __restrict__ v, const float* __restrict__ rph,
    const float* __restrict__ rpw, float* __restrict__ ao)
{
  __shared__ float qs[48][68];
  __shared__ float kst[64][68];   // transposed: [d][key]
  __shared__ float vs[64][68];    // [key][d]
  __shared__ float ps[48][68];    // P [q-row][key-in-tile]
  __shared__ float bhs[48][48];
  __shared__ float bws[48][48];

  const int tid = threadIdx.x;
  const int lane = tid & 63;
  const int wid = tid >> 6;
  const int w0 = wid * 12;        // wave owns q-rows w0..w0+11
  const int qh = blockIdx.x;      // 0..47
  const int bh = blockIdx.y;      // 0..23

  const float* qb = q + (size_t)bh * SEQ * HD;
  const float* kb = k + (size_t)bh * SEQ * HD;
  const float* vb = v + (size_t)bh * SEQ * HD;
  const int s0 = qh * 48;

  // load Q tile
  for (int i = tid; i < 48*16; i += 256) {
    int row = i >> 4, d4 = (i & 15) * 4;
    *(float4*)&qs[row][d4] = *(const float4*)(qb + (size_t)(s0+row)*HD + d4);
  }
  __syncthreads();

  // decomposed rel-pos bias tables: bhs[w][kh] = q_w . Rh[qh,kh]; bws[w][kw] = q_w . Rw[w,kw]
  for (int i = tid; i < 48*48; i += 256) {
    int ww = i / 48, kx = i - (i/48)*48;
    const float* r1 = rph + (size_t)(qh - kx + 47) * HD;
    const float* r2 = rpw + (size_t)(ww - kx + 47) * HD;
    float s1 = 0.f, s2 = 0.f;
#pragma unroll 4
    for (int d4 = 0; d4 < 64; d4 += 4) {
      F4 qq; qq.v = *(float4*)&qs[ww][d4];
      F4 a;  a.v  = *(const float4*)(r1 + d4);
      F4 bb; bb.v = *(const float4*)(r2 + d4);
#pragma unroll
      for (int e = 0; e < 4; e++) { s1 += qq.f[e]*a.f[e]; s2 += qq.f[e]*bb.f[e]; }
    }
    bhs[ww][kx] = s1;
    bws[ww][kx] = s2;
  }

  float m_r[12], l_r[12], o_r[12];
#pragma unroll
  for (int i = 0; i < 12; i++) { m_r[i] = -3.0e38f; l_r[i] = 0.f; o_r[i] = 0.f; }

  for (int kt = 0; kt < 36; kt++) {
    // stage K (transposed) and V tiles
    {
      int key = tid & 63, dh = (tid >> 6) * 16;
      const float* kp = kb + (size_t)(kt*64 + key)*HD + dh;
      const float* vp = vb + (size_t)(kt*64 + key)*HD + dh;
#pragma unroll
      for (int i = 0; i < 4; i++) {
        F4 kv; kv.v = *(const float4*)(kp + i*4);
        float4 vv4 = *(const float4*)(vp + i*4);
        *(float4*)&vs[key][dh + i*4] = vv4;
        kst[dh+i*4+0][key] = kv.f[0];
        kst[dh+i*4+1][key] = kv.f[1];
        kst[dh+i*4+2][key] = kv.f[2];
        kst[dh+i*4+3][key] = kv.f[3];
      }
    }
    __syncthreads();

    // QK^T: lane = key column, 12 q-rows per wave
    float acc[12];
#pragma unroll
    for (int i = 0; i < 12; i++) acc[i] = 0.f;
#pragma unroll 4
    for (int d4 = 0; d4 < 64; d4 += 4) {
      float k0v = kst[d4+0][lane];
      float k1v = kst[d4+1][lane];
      float k2v = kst[d4+2][lane];
      float k3v = kst[d4+3][lane];
#pragma unroll
      for (int ww = 0; ww < 12; ww++) {
        F4 qq; qq.v = *(float4*)&qs[w0+ww][d4];
        acc[ww] += qq.f[0]*k0v + qq.f[1]*k1v + qq.f[2]*k2v + qq.f[3]*k3v;
      }
    }

    const int kg = kt*64 + lane;
    const int kh = kg / 48;
    const int kw = kg - kh*48;
#pragma unroll
    for (int ww = 0; ww < 12; ww++) {
      float logit = acc[ww] * 0.125f + bhs[w0+ww][kh] + bws[w0+ww][kw];
      float mx = logit;
#pragma unroll
      for (int off = 32; off > 0; off >>= 1)
        mx = fmaxf(mx, __shfl_xor(mx, off));
      float mnew = fmaxf(m_r[ww], mx);
      float corr = __expf(m_r[ww] - mnew);
      float p = __expf(logit - mnew);
      float sum = p;
#pragma unroll
      for (int off = 32; off > 0; off >>= 1)
        sum += __shfl_xor(sum, off);
      l_r[ww] = l_r[ww] * corr + sum;
      m_r[ww] = mnew;
      o_r[ww] *= corr;
      ps[w0+ww][lane] = p;   // same-wave LDS, in-order: no barrier needed
    }

    // PV: o[w][lane] += sum_j P[w][j] * V[j][lane]
#pragma unroll 4
    for (int j4 = 0; j4 < 64; j4 += 4) {
      float v0 = vs[j4+0][lane];
      float v1 = vs[j4+1][lane];
      float v2 = vs[j4+2][lane];
      float v3 = vs[j4+3][lane];
#pragma unroll
      for (int ww = 0; ww < 12; ww++) {
        F4 pp; pp.v = *(float4*)&ps[w0+ww][j4];
        o_r[ww] += pp.f[0]*v0 + pp.f[1]*v1 + pp.f[2]*v2 + pp.f[3]*v3;
      }
    }
    __syncthreads();
  }

  const int b = bh / 12, head = bh - (bh/12)*12;
#pragma unroll
  for (int ww = 0; ww < 12; ww++) {
    int s = s0 + w0 + ww;
    ao[((size_t)b*SEQ + s)*768 + head*64 + lane] = o_r[ww] / l_r[ww];
  }
}

// ---------------- proj GEMM: [4608x768] @ [768x768] + bias -> out
__global__ __launch_bounds__(256) void proj_gemm_k(
    const float* __restrict__ a, const float* __restrict__ w,
    const float* __restrict__ bias, float* __restrict__ out)
{
  __shared__ float As[16][68];
  __shared__ float Bs[16][68];
  const int tid = threadIdx.x;
  const int tn = tid & 15, tm = tid >> 4;
  const int c0 = blockIdx.x * 64;   // 12 blocks
  const int r0 = blockIdx.y * 64;   // 72 blocks
  const int arow = tid >> 2, ak4 = (tid & 3) * 4;
  const int brow = tid >> 4, bc4 = (tid & 15) * 4;
  float acc[4][4] = {};
  const float* ap = a + (size_t)(r0 + arow) * 768 + ak4;
  const float* bp = w + (size_t)brow * 768 + c0 + bc4;
  for (int k0 = 0; k0 < 768; k0 += 16) {
    F4 a4, b4;
    a4.v = *(const float4*)(ap + k0);
    b4.v = *(const float4*)(bp + (size_t)k0 * 768);
    __syncthreads();
    As[ak4+0][arow] = a4.f[0];
    As[ak4+1][arow] = a4.f[1];
    As[ak4+2][arow] = a4.f[2];
    As[ak4+3][arow] = a4.f[3];
    *(float4*)&Bs[brow][bc4] = b4.v;
    __syncthreads();
#pragma unroll
    for (int p = 0; p < 16; p++) {
      F4 av, bv;
      av.v = *(float4*)&As[p][tm*4];
      bv.v = *(float4*)&Bs[p][tn*4];
#pragma unroll
      for (int i = 0; i < 4; i++)
#pragma unroll
        for (int j = 0; j < 4; j++)
          acc[i][j] += av.f[i] * bv.f[j];
    }
  }
  float bb[4];
#pragma unroll
  for (int j = 0; j < 4; j++) bb[j] = bias[c0 + tn*4 + j];
#pragma unroll
  for (int i = 0; i < 4; i++) {
    int row = r0 + tm*4 + i;
    F4 ov;
#pragma unroll
    for (int j = 0; j < 4; j++) ov.f[j] = acc[i][j] + bb[j];
    *(float4*)(out + (size_t)row * 768 + c0 + tn*4) = ov.v;
  }
}

extern "C" void kernel_launch(void* const* d_in, const int* in_sizes, int n_in,
                              void* d_out, int out_size, void* d_ws, size_t ws_size,
                              hipStream_t stream) {
  const float* x      = (const float*)d_in[0];
  const float* qkv_w  = (const float*)d_in[1];
  const float* qkv_b  = (const float*)d_in[2];
  const float* proj_w = (const float*)d_in[3];
  const float* proj_b = (const float*)d_in[4];
  const float* rph    = (const float*)d_in[5];
  const float* rpw    = (const float*)d_in[6];
  float* out = (float*)d_out;
  float* ws  = (float*)d_ws;

  const size_t SZ = (size_t)24 * SEQ * HD;   // 3,538,944 floats
  float* q  = ws;
  float* k  = ws + SZ;
  float* v  = ws + 2*SZ;
  float* ao = ws + 3*SZ;                     // [B][S][768] attention output

  qkv_gemm_k<<<dim3(36, 72), 256, 0, stream>>>(x, qkv_w, qkv_b, q, k, v);
  attn_k    <<<dim3(48, 24), 256, 0, stream>>>(q, k, v, rph, rpw, ao);
  proj_gemm_k<<<dim3(12, 72), 256, 0, stream>>>(ao, proj_w, proj_b, out);
}

// Round 2
// 792.714 us; speedup vs baseline: 2.4557x; 2.4557x over previous
//
#include <hip/hip_runtime.h>
#include <hip/hip_fp16.h>

#define HD 64
#define SEQ 2304

typedef unsigned short u16;
typedef unsigned int u32;
using f32x4 = __attribute__((ext_vector_type(4))) float;
using s16x8 = __attribute__((ext_vector_type(8))) short;

union F4 { float4 v; float f[4]; };

static __device__ __forceinline__ u16 f2bf(float x) {
  union { float f; u32 u; } a; a.f = x;
  u32 r = a.u + 0x7fffu + ((a.u >> 16) & 1u);
  return (u16)(r >> 16);
}
static __device__ __forceinline__ float bf2f(u16 h) {
  union { float f; u32 u; } a; a.u = ((u32)h) << 16; return a.f;
}

// ---------------- QKV GEMM: [4608x768] @ [768x2304] + bias
// q -> fp32 [24][2304][64]; k,v -> bf16 hi/lo [24][2304][64]
__global__ __launch_bounds__(256) void qkv_gemm_k(
    const float* __restrict__ x, const float* __restrict__ w,
    const float* __restrict__ bias,
    float* __restrict__ qbuf, u16* __restrict__ khi, u16* __restrict__ klo,
    u16* __restrict__ vhi, u16* __restrict__ vlo)
{
  __shared__ float As[16][68];
  __shared__ float Bs[16][68];
  const int tid = threadIdx.x;
  const int tn = tid & 15, tm = tid >> 4;
  const int c0 = blockIdx.x * 64;   // 36 blocks
  const int r0 = blockIdx.y * 64;   // 72 blocks
  const int arow = tid >> 2, ak4 = (tid & 3) * 4;
  const int brow = tid >> 4, bc4 = (tid & 15) * 4;
  float acc[4][4] = {};
  const float* ap = x + (size_t)(r0 + arow) * 768 + ak4;
  const float* bp = w + (size_t)brow * 2304 + c0 + bc4;
  for (int k0 = 0; k0 < 768; k0 += 16) {
    F4 a4, b4;
    a4.v = *(const float4*)(ap + k0);
    b4.v = *(const float4*)(bp + (size_t)k0 * 2304);
    __syncthreads();
    As[ak4+0][arow] = a4.f[0];
    As[ak4+1][arow] = a4.f[1];
    As[ak4+2][arow] = a4.f[2];
    As[ak4+3][arow] = a4.f[3];
    *(float4*)&Bs[brow][bc4] = b4.v;
    __syncthreads();
#pragma unroll
    for (int p = 0; p < 16; p++) {
      F4 av, bv;
      av.v = *(float4*)&As[p][tm*4];
      bv.v = *(float4*)&Bs[p][tn*4];
#pragma unroll
      for (int i = 0; i < 4; i++)
#pragma unroll
        for (int j = 0; j < 4; j++)
          acc[i][j] += av.f[i] * bv.f[j];
    }
  }
  const int hg = blockIdx.x;
  const int which = hg / 12, head = hg - (hg / 12) * 12;
  const int b = r0 / 2304;
  const int bh = b * 12 + head;
  float bb[4];
#pragma unroll
  for (int j = 0; j < 4; j++) bb[j] = bias[c0 + tn*4 + j];
  if (which == 0) {
#pragma unroll
    for (int i = 0; i < 4; i++) {
      int row = r0 + tm*4 + i;
      int s = row - b * 2304;
      F4 ov;
#pragma unroll
      for (int j = 0; j < 4; j++) ov.f[j] = acc[i][j] + bb[j];
      *(float4*)(qbuf + ((size_t)bh * SEQ + s) * 64 + tn*4) = ov.v;
    }
  } else {
    u16* dhi = (which == 1) ? khi : vhi;
    u16* dlo = (which == 1) ? klo : vlo;
#pragma unroll
    for (int i = 0; i < 4; i++) {
      int row = r0 + tm*4 + i;
      int s = row - b * 2304;
      u32 h01 = 0, h23 = 0, l01 = 0, l23 = 0;
#pragma unroll
      for (int j = 0; j < 4; j++) {
        float xx = acc[i][j] + bb[j];
        u16 hi = f2bf(xx);
        u16 lo = f2bf(xx - bf2f(hi));
        if (j < 2) { h01 |= ((u32)hi) << (16*j); l01 |= ((u32)lo) << (16*j); }
        else       { h23 |= ((u32)hi) << (16*(j-2)); l23 |= ((u32)lo) << (16*(j-2)); }
      }
      size_t off = ((size_t)bh * SEQ + s) * 64 + tn*4;
      uint2 hv; hv.x = h01; hv.y = h23;
      uint2 lv; lv.x = l01; lv.y = l23;
      *(uint2*)(dhi + off) = hv;
      *(uint2*)(dlo + off) = lv;
    }
  }
}

// ---------------- Fused attention: split-bf16 MFMA, swapped QK^T, online softmax
__global__ __launch_bounds__(512) void attn_k(
    const float* __restrict__ qb,
    const u16* __restrict__ khi, const u16* __restrict__ klo,
    const u16* __restrict__ vhi, const u16* __restrict__ vlo,
    const float* __restrict__ rph, const float* __restrict__ rpw,
    float* __restrict__ ao)
{
  __shared__ __align__(16) char pool[49408];
  u16* Khi = (u16*)pool;              // [64 key][72 d]
  u16* Klo = (u16*)(pool + 9216);
  u16* VhT = (u16*)(pool + 18432);    // [64 d][72 key]
  u16* VlT = (u16*)(pool + 27648);
  __half* Bh = (__half*)(pool + 36864);  // [64 q][49 kh]
  __half* Bw = (__half*)(pool + 43136);  // [64 q][49 kw]
  float* qlds = (float*)pool;         // prologue alias [64][68] f32
  float* o_s  = (float*)pool;         // epilogue alias [64][68] f32
  float* m_s  = (float*)(pool + 17408);  // [64]
  float* l_s  = (float*)(pool + 17664);  // [64]

  const int tid  = threadIdx.x;
  const int lane = tid & 63;
  const int wid  = tid >> 6;
  const int g    = lane >> 4;
  const int ql   = lane & 15;
  const int wq   = wid & 3;     // q-group: rows [16*wq, 16*wq+16)
  const int hh   = wid >> 2;    // key-half stream: keys [32*hh, 32*hh+32) per tile
  const int qt   = blockIdx.x;  // 36
  const int bh   = blockIdx.y;  // 24
  const int s0   = qt * 64;
  const size_t base = (size_t)bh * SEQ * HD;

  // ---- stage Q tile fp32 -> LDS
  {
    int row = tid >> 3, c0 = (tid & 7) * 8;
    const float* src = qb + base + (size_t)(s0 + row) * HD + c0;
    f32x4 v0 = *(const f32x4*)src;
    f32x4 v1 = *(const f32x4*)(src + 4);
    *(f32x4*)&qlds[row * 68 + c0]     = v0;
    *(f32x4*)&qlds[row * 68 + c0 + 4] = v1;
  }
  __syncthreads();

  // ---- Q fragments hi/lo (this wave's 16 q-rows; lane's q = 16*wq + ql)
  s16x8 qfh[2], qfl[2];
  {
    int qrow = wq * 16 + ql;
#pragma unroll
    for (int ds = 0; ds < 2; ds++) {
#pragma unroll
      for (int h2 = 0; h2 < 2; h2++) {
        f32x4 qv = *(const f32x4*)&qlds[qrow * 68 + g * 4 + h2 * 16 + ds * 32];
#pragma unroll
        for (int j = 0; j < 4; j++) {
          float xx = qv[j];
          u16 hi = f2bf(xx);
          u16 lo = f2bf(xx - bf2f(hi));
          qfh[ds][h2 * 4 + j] = (short)hi;
          qfl[ds][h2 * 4 + j] = (short)lo;
        }
      }
    }
  }

  // ---- decomposed rel-pos bias tables (fp16): Bh[q][kh], Bw[q][kw]
  for (int i = tid; i < 64 * 96; i += 512) {
    int q = i / 96, j = i - (i / 96) * 96;
    int s = s0 + q;
    int qhg = s / 48, qw = s - qhg * 48;
    const float* tab;
    int ridx, col;
    if (j < 48) { col = j;      ridx = qhg - j + 47;        tab = rph; }
    else        { col = j - 48; ridx = qw - (j - 48) + 47;  tab = rpw; }
    const float* rp = tab + (size_t)ridx * HD;
    const float* qp = &qlds[q * 68];
    float s1 = 0.f;
#pragma unroll 4
    for (int d = 0; d < 64; d += 4) {
      f32x4 a = *(const f32x4*)(qp + d);
      f32x4 bv = *(const f32x4*)(rp + d);
      s1 += a[0]*bv[0] + a[1]*bv[1] + a[2]*bv[2] + a[3]*bv[3];
    }
    if (j < 48) Bh[q * 49 + col] = __float2half_rn(s1);
    else        Bw[q * 49 + col] = __float2half_rn(s1);
  }
  __syncthreads();

  float m_r = -3.0e38f, l_r = 0.f;
  f32x4 oacc[4] = {};   // O[q = 4g+r][d = ql + 16*dt]

  for (int kt = 0; kt < 36; kt++) {
    // ---- stage K (row-major hi/lo) and V (transposed hi/lo)
    {
      int key = tid & 63, sel = tid >> 6;
      int arr = sel >> 2, dq = (sel & 3) * 16;
      const u16* src = (arr ? klo : khi) + base + (size_t)(kt * 64 + key) * HD + dq;
      uint4 a0 = *(const uint4*)src;
      uint4 a1 = *(const uint4*)(src + 8);
      u16* dst = (arr ? Klo : Khi) + key * 72 + dq;
      *(uint4*)dst = a0;
      *(uint4*)(dst + 8) = a1;
      int dv0 = sel * 8;
      const u16* sh = vhi + base + (size_t)(kt * 64 + key) * HD + dv0;
      const u16* sl = vlo + base + (size_t)(kt * 64 + key) * HD + dv0;
      uint4 vh4 = *(const uint4*)sh;
      uint4 vl4 = *(const uint4*)sl;
      const u16* ph = (const u16*)&vh4;
      const u16* pl = (const u16*)&vl4;
#pragma unroll
      for (int e = 0; e < 8; e++) {
        VhT[(dv0 + e) * 72 + key] = ph[e];
        VlT[(dv0 + e) * 72 + key] = pl[e];
      }
    }
    __syncthreads();

    // ---- QK^T (swapped): S^T[key][q], keys = kt*64 + 32*hh + [0,32)
    f32x4 sacc[2] = {};
#pragma unroll
    for (int ds = 0; ds < 2; ds++) {
#pragma unroll
      for (int t2 = 0; t2 < 2; t2++) {
        int row = (hh * 2 + t2) * 16 + ql;
        const u16* ph = Khi + row * 72 + g * 4 + ds * 32;
        const u16* pl = Klo + row * 72 + g * 4 + ds * 32;
        union { uint2 u[2]; s16x8 v; } af, al;
        af.u[0] = *(const uint2*)ph; af.u[1] = *(const uint2*)(ph + 16);
        al.u[0] = *(const uint2*)pl; al.u[1] = *(const uint2*)(pl + 16);
        sacc[t2] = __builtin_amdgcn_mfma_f32_16x16x32_bf16(af.v, qfh[ds], sacc[t2], 0, 0, 0);
        sacc[t2] = __builtin_amdgcn_mfma_f32_16x16x32_bf16(af.v, qfl[ds], sacc[t2], 0, 0, 0);
        sacc[t2] = __builtin_amdgcn_mfma_f32_16x16x32_bf16(al.v, qfh[ds], sacc[t2], 0, 0, 0);
      }
    }

    // ---- bias + online softmax (lane owns q = 16*wq + ql; 8 keys in-lane)
    const int q64 = wq * 16 + ql;
    float p[8];
    float tmax = -3.0e38f;
#pragma unroll
    for (int t2 = 0; t2 < 2; t2++)
#pragma unroll
      for (int r = 0; r < 4; r++) {
        u32 kg = (u32)(kt * 64 + hh * 32 + t2 * 16 + g * 4 + r);
        u32 kh = kg / 48u;
        u32 kw = kg - kh * 48u;
        float lg = sacc[t2][r] * 0.125f
                 + __half2float(Bh[q64 * 49 + (int)kh])
                 + __half2float(Bw[q64 * 49 + (int)kw]);
        p[t2 * 4 + r] = lg;
        tmax = fmaxf(tmax, lg);
      }
    tmax = fmaxf(tmax, __shfl_xor(tmax, 16));
    tmax = fmaxf(tmax, __shfl_xor(tmax, 32));
    float mnew = fmaxf(m_r, tmax);
    float corr = __expf(m_r - mnew);
    m_r = mnew;
    float psum = 0.f;
#pragma unroll
    for (int j = 0; j < 8; j++) { p[j] = __expf(p[j] - mnew); psum += p[j]; }
    psum += __shfl_xor(psum, 16);
    psum += __shfl_xor(psum, 32);
    l_r = l_r * corr + psum;

    float cq[4];
#pragma unroll
    for (int r = 0; r < 4; r++) cq[r] = __shfl(corr, g * 4 + r);
#pragma unroll
    for (int dt = 0; dt < 4; dt++)
#pragma unroll
      for (int r = 0; r < 4; r++) oacc[dt][r] *= cq[r];

    // ---- P fragments hi/lo (in-register: S^T regs == PV A-frag slots)
    s16x8 pfh, pfl;
#pragma unroll
    for (int j = 0; j < 8; j++) {
      u16 hi = f2bf(p[j]);
      u16 lo = f2bf(p[j] - bf2f(hi));
      pfh[j] = (short)hi;
      pfl[j] = (short)lo;
    }

    // ---- PV: O[q][d] += P^T... A=P (M=q,K=32 keys), B=V (keys x d)
#pragma unroll
    for (int dt = 0; dt < 4; dt++) {
      int row = ql + 16 * dt;
      const u16* ph = VhT + row * 72 + hh * 32 + g * 4;
      const u16* pl = VlT + row * 72 + hh * 32 + g * 4;
      union { uint2 u[2]; s16x8 v; } bhf, blf;
      bhf.u[0] = *(const uint2*)ph; bhf.u[1] = *(const uint2*)(ph + 16);
      blf.u[0] = *(const uint2*)pl; blf.u[1] = *(const uint2*)(pl + 16);
      oacc[dt] = __builtin_amdgcn_mfma_f32_16x16x32_bf16(pfh, bhf.v, oacc[dt], 0, 0, 0);
      oacc[dt] = __builtin_amdgcn_mfma_f32_16x16x32_bf16(pfh, blf.v, oacc[dt], 0, 0, 0);
      oacc[dt] = __builtin_amdgcn_mfma_f32_16x16x32_bf16(pfl, bhf.v, oacc[dt], 0, 0, 0);
    }
    __syncthreads();
  }

  // ---- merge the two key-streams per q-group, write out
  if (hh == 1) {
    if (g == 0) { m_s[wq * 16 + ql] = m_r; l_s[wq * 16 + ql] = l_r; }
#pragma unroll
    for (int dt = 0; dt < 4; dt++)
#pragma unroll
      for (int r = 0; r < 4; r++)
        o_s[(wq * 16 + g * 4 + r) * 68 + ql + 16 * dt] = oacc[dt][r];
  }
  __syncthreads();
  if (hh == 0) {
    float m2 = m_s[wq * 16 + ql];
    float l2 = l_s[wq * 16 + ql];
    float mf = fmaxf(m_r, m2);
    float c1 = __expf(m_r - mf);
    float c2 = __expf(m2 - mf);
    float lf = l_r * c1 + l2 * c2;
    float c1q[4], c2q[4], lfq[4];
#pragma unroll
    for (int r = 0; r < 4; r++) {
      c1q[r] = __shfl(c1, g * 4 + r);
      c2q[r] = __shfl(c2, g * 4 + r);
      lfq[r] = __shfl(lf, g * 4 + r);
    }
    const int b = bh / 12, head = bh - (bh / 12) * 12;
#pragma unroll
    for (int dt = 0; dt < 4; dt++)
#pragma unroll
      for (int r = 0; r < 4; r++) {
        float oo = oacc[dt][r] * c1q[r]
                 + o_s[(wq * 16 + g * 4 + r) * 68 + ql + 16 * dt] * c2q[r];
        int s = s0 + wq * 16 + g * 4 + r;
        ao[((size_t)b * SEQ + s) * 768 + head * 64 + ql + 16 * dt] = oo / lfq[r];
      }
  }
}

// ---------------- proj GEMM: [4608x768] @ [768x768] + bias -> out
__global__ __launch_bounds__(256) void proj_gemm_k(
    const float* __restrict__ a, const float* __restrict__ w,
    const float* __restrict__ bias, float* __restrict__ out)
{
  __shared__ float As[16][68];
  __shared__ float Bs[16][68];
  const int tid = threadIdx.x;
  const int tn = tid & 15, tm = tid >> 4;
  const int c0 = blockIdx.x * 64;
  const int r0 = blockIdx.y * 64;
  const int arow = tid >> 2, ak4 = (tid & 3) * 4;
  const int brow = tid >> 4, bc4 = (tid & 15) * 4;
  float acc[4][4] = {};
  const float* ap = a + (size_t)(r0 + arow) * 768 + ak4;
  const float* bp = w + (size_t)brow * 768 + c0 + bc4;
  for (int k0 = 0; k0 < 768; k0 += 16) {
    F4 a4, b4;
    a4.v = *(const float4*)(ap + k0);
    b4.v = *(const float4*)(bp + (size_t)k0 * 768);
    __syncthreads();
    As[ak4+0][arow] = a4.f[0];
    As[ak4+1][arow] = a4.f[1];
    As[ak4+2][arow] = a4.f[2];
    As[ak4+3][arow] = a4.f[3];
    *(float4*)&Bs[brow][bc4] = b4.v;
    __syncthreads();
#pragma unroll
    for (int p = 0; p < 16; p++) {
      F4 av, bv;
      av.v = *(float4*)&As[p][tm*4];
      bv.v = *(float4*)&Bs[p][tn*4];
#pragma unroll
      for (int i = 0; i < 4; i++)
#pragma unroll
        for (int j = 0; j < 4; j++)
          acc[i][j] += av.f[i] * bv.f[j];
    }
  }
  float bb[4];
#pragma unroll
  for (int j = 0; j < 4; j++) bb[j] = bias[c0 + tn*4 + j];
#pragma unroll
  for (int i = 0; i < 4; i++) {
    int row = r0 + tm*4 + i;
    F4 ov;
#pragma unroll
    for (int j = 0; j < 4; j++) ov.f[j] = acc[i][j] + bb[j];
    *(float4*)(out + (size_t)row * 768 + c0 + tn*4) = ov.v;
  }
}

extern "C" void kernel_launch(void* const* d_in, const int* in_sizes, int n_in,
                              void* d_out, int out_size, void* d_ws, size_t ws_size,
                              hipStream_t stream) {
  const float* x      = (const float*)d_in[0];
  const float* qkv_w  = (const float*)d_in[1];
  const float* qkv_b  = (const float*)d_in[2];
  const float* proj_w = (const float*)d_in[3];
  const float* proj_b = (const float*)d_in[4];
  const float* rph    = (const float*)d_in[5];
  const float* rpw    = (const float*)d_in[6];
  float* out = (float*)d_out;
  float* ws  = (float*)d_ws;

  const size_t SZ = (size_t)24 * SEQ * HD;   // 3,538,944 elems
  float* qbuf = ws;                          // SZ f32
  u16* khi = (u16*)(ws + SZ);                // 4 x SZ u16 == 2 x SZ f32
  u16* klo = khi + SZ;
  u16* vhi = klo + SZ;
  u16* vlo = vhi + SZ;
  float* ao = ws + 3 * SZ;                   // SZ f32

  qkv_gemm_k<<<dim3(36, 72), 256, 0, stream>>>(x, qkv_w, qkv_b, qbuf, khi, klo, vhi, vlo);
  attn_k    <<<dim3(36, 24), 512, 0, stream>>>(qbuf, khi, klo, vhi, vlo, rph, rpw, ao);
  proj_gemm_k<<<dim3(12, 72), 256, 0, stream>>>(ao, proj_w, proj_b, out);
}

// Round 3
// 662.208 us; speedup vs baseline: 2.9396x; 1.1971x over previous
//
#include <hip/hip_runtime.h>
#include <hip/hip_fp16.h>

#define HD 64
#define SEQ 2304

typedef unsigned short u16;
typedef unsigned int u32;
using f32x4 = __attribute__((ext_vector_type(4))) float;
using s16x8 = __attribute__((ext_vector_type(8))) short;

union F4 { float4 v; float f[4]; };

static __device__ __forceinline__ u16 f2bf(float x) {
  union { float f; u32 u; } a; a.f = x;
  u32 r = a.u + 0x7fffu + ((a.u >> 16) & 1u);
  return (u16)(r >> 16);
}
static __device__ __forceinline__ float bf2f(u16 h) {
  union { float f; u32 u; } a; a.u = ((u32)h) << 16; return a.f;
}

// ---------------- QKV GEMM: [4608x768] @ [768x2304] + bias
// q -> fp32 [24][2304][64]
// k -> bf16 hi/lo tile-images [bh][kt][key 64][pc(d) 64]   (pc: k-field permuted)
// v -> bf16 hi/lo transposed tile-images [bh][kt][d 64][vc(key) 64]
__global__ __launch_bounds__(256) void qkv_gemm_k(
    const float* __restrict__ x, const float* __restrict__ w,
    const float* __restrict__ bias,
    float* __restrict__ qbuf, u16* __restrict__ khi, u16* __restrict__ klo,
    u16* __restrict__ vhi, u16* __restrict__ vlo)
{
  __shared__ float As[16][68];
  __shared__ float Bs[16][68];
  const int tid = threadIdx.x;
  const int tn = tid & 15, tm = tid >> 4;
  const int c0 = blockIdx.x * 64;   // 36 blocks
  const int r0 = blockIdx.y * 64;   // 72 blocks
  const int arow = tid >> 2, ak4 = (tid & 3) * 4;
  const int brow = tid >> 4, bc4 = (tid & 15) * 4;
  float acc[4][4] = {};
  const float* ap = x + (size_t)(r0 + arow) * 768 + ak4;
  const float* bp = w + (size_t)brow * 2304 + c0 + bc4;
  for (int k0 = 0; k0 < 768; k0 += 16) {
    F4 a4, b4;
    a4.v = *(const float4*)(ap + k0);
    b4.v = *(const float4*)(bp + (size_t)k0 * 2304);
    __syncthreads();
    As[ak4+0][arow] = a4.f[0];
    As[ak4+1][arow] = a4.f[1];
    As[ak4+2][arow] = a4.f[2];
    As[ak4+3][arow] = a4.f[3];
    *(float4*)&Bs[brow][bc4] = b4.v;
    __syncthreads();
#pragma unroll
    for (int p = 0; p < 16; p++) {
      F4 av, bv;
      av.v = *(float4*)&As[p][tm*4];
      bv.v = *(float4*)&Bs[p][tn*4];
#pragma unroll
      for (int i = 0; i < 4; i++)
#pragma unroll
        for (int j = 0; j < 4; j++)
          acc[i][j] += av.f[i] * bv.f[j];
    }
  }
  const int hg = blockIdx.x;
  const int which = hg / 12, head = hg - (hg / 12) * 12;
  const int b = r0 / 2304;
  const int bh = b * 12 + head;
  float bb[4];
#pragma unroll
  for (int j = 0; j < 4; j++) bb[j] = bias[c0 + tn*4 + j];
  if (which == 0) {
#pragma unroll
    for (int i = 0; i < 4; i++) {
      int row = r0 + tm*4 + i;
      int s = row - b * 2304;
      F4 ov;
#pragma unroll
      for (int j = 0; j < 4; j++) ov.f[j] = acc[i][j] + bb[j];
      *(float4*)(qbuf + ((size_t)bh * SEQ + s) * 64 + tn*4) = ov.v;
    }
  } else {
    u16 hb[4][4], lb[4][4];
#pragma unroll
    for (int i = 0; i < 4; i++)
#pragma unroll
      for (int j = 0; j < 4; j++) {
        float xx = acc[i][j] + bb[j];
        u16 h = f2bf(xx);
        hb[i][j] = h;
        lb[i][j] = f2bf(xx - bf2f(h));
      }
    const int kt = (r0 - b * 2304) >> 6;   // r0 is 64-aligned within batch
    const size_t tile = ((size_t)bh * 36 + kt) * 4096;
    if (which == 1) {
      // K image: [key][pc(d)]; d = tn*4+j -> pc0 contiguous in j
      const int pc0 = (tn >> 3) * 32 + (tn & 3) * 8 + ((tn >> 2) & 1) * 4;
#pragma unroll
      for (int i = 0; i < 4; i++) {
        int key = tm * 4 + i;
        uint2 hv, lv;
        hv.x = (u32)hb[i][0] | ((u32)hb[i][1] << 16);
        hv.y = (u32)hb[i][2] | ((u32)hb[i][3] << 16);
        lv.x = (u32)lb[i][0] | ((u32)lb[i][1] << 16);
        lv.y = (u32)lb[i][2] | ((u32)lb[i][3] << 16);
        *(uint2*)(khi + tile + key * 64 + pc0) = hv;
        *(uint2*)(klo + tile + key * 64 + pc0) = lv;
      }
    } else {
      // V^T image: [d][vc(key)]; key = tm*4+i -> vc0 contiguous in i
      const int vc0 = (tm >> 3) * 32 + (tm & 3) * 8 + ((tm >> 2) & 1) * 4;
#pragma unroll
      for (int j = 0; j < 4; j++) {
        int d = tn * 4 + j;
        uint2 hv, lv;
        hv.x = (u32)hb[0][j] | ((u32)hb[1][j] << 16);
        hv.y = (u32)hb[2][j] | ((u32)hb[3][j] << 16);
        lv.x = (u32)lb[0][j] | ((u32)lb[1][j] << 16);
        lv.y = (u32)lb[2][j] | ((u32)lb[3][j] << 16);
        *(uint2*)(vhi + tile + d * 64 + vc0) = hv;
        *(uint2*)(vlo + tile + d * 64 + vc0) = lv;
      }
    }
  }
}

// ---------------- Fused attention: split-bf16 MFMA, swapped QK^T, online softmax
// LDS images pre-permuted so every MFMA fragment is one contiguous ds_read_b128,
// conflict-free at 72-u16 row stride. Staging = vectorized copy w/ reg prefetch.
__global__ __launch_bounds__(512) void attn_k(
    const float* __restrict__ qb,
    const u16* __restrict__ khi, const u16* __restrict__ klo,
    const u16* __restrict__ vhi, const u16* __restrict__ vlo,
    const float* __restrict__ rph, const float* __restrict__ rpw,
    float* __restrict__ ao)
{
  __shared__ __align__(16) char pool[49920];
  u16* KhiL = (u16*)pool;              // [64 key][72]
  u16* KloL = (u16*)(pool + 9216);
  u16* VhL  = (u16*)(pool + 18432);    // [64 d][72]
  u16* VlL  = (u16*)(pool + 27648);
  __half* Bh = (__half*)(pool + 36864);   // [64 q][49]
  __half* Bw = (__half*)(pool + 43136);   // [64 q][49]
  float* m_s = (float*)(pool + 49408);    // [64]
  float* l_s = (float*)(pool + 49664);    // [64]
  float* qlds = (float*)pool;             // prologue alias [64][68] f32
  float* o_s  = (float*)pool;             // epilogue alias [64][68] f32

  const int tid  = threadIdx.x;
  const int lane = tid & 63;
  const int wid  = tid >> 6;
  const int g    = lane >> 4;
  const int ql   = lane & 15;
  const int wq   = wid & 3;     // q-group: rows [16*wq, 16*wq+16)
  const int hh   = wid >> 2;    // key-half stream
  const int qt   = blockIdx.x;  // 36
  const int bh   = blockIdx.y;  // 24
  const int s0   = qt * 64;

  // ---- stage Q tile fp32 -> LDS
  {
    int row = tid >> 3, c0 = (tid & 7) * 8;
    const float* src = qb + ((size_t)bh * SEQ + s0 + row) * HD + c0;
    f32x4 v0 = *(const f32x4*)src;
    f32x4 v1 = *(const f32x4*)(src + 4);
    *(f32x4*)&qlds[row * 68 + c0]     = v0;
    *(f32x4*)&qlds[row * 68 + c0 + 4] = v1;
  }
  __syncthreads();

  // ---- Q fragments hi/lo (lane's q = 16*wq + ql)
  s16x8 qfh[2], qfl[2];
  {
    int qrow = wq * 16 + ql;
#pragma unroll
    for (int ds = 0; ds < 2; ds++) {
#pragma unroll
      for (int h2 = 0; h2 < 2; h2++) {
        f32x4 qv = *(const f32x4*)&qlds[qrow * 68 + g * 4 + h2 * 16 + ds * 32];
#pragma unroll
        for (int j = 0; j < 4; j++) {
          float xx = qv[j];
          u16 hi = f2bf(xx);
          u16 lo = f2bf(xx - bf2f(hi));
          qfh[ds][h2 * 4 + j] = (short)hi;
          qfl[ds][h2 * 4 + j] = (short)lo;
        }
      }
    }
  }

  // ---- prefetch tile 0 (hides under bias-table compute)
  const size_t tbK = (size_t)bh * 36 * 4096;
  const int srow = tid >> 3, sch = tid & 7;
  const size_t soff = (size_t)srow * 64 + sch * 8;
  uint4 rkh = *(const uint4*)(khi + tbK + soff);
  uint4 rkl = *(const uint4*)(klo + tbK + soff);
  uint4 rvh = *(const uint4*)(vhi + tbK + soff);
  uint4 rvl = *(const uint4*)(vlo + tbK + soff);

  // ---- decomposed rel-pos bias tables (fp16)
  for (int i = tid; i < 64 * 96; i += 512) {
    int q = i / 96, j = i - (i / 96) * 96;
    int s = s0 + q;
    int qhg = s / 48, qw = s - qhg * 48;
    const float* tab;
    int ridx, col;
    if (j < 48) { col = j;      ridx = qhg - j + 47;        tab = rph; }
    else        { col = j - 48; ridx = qw - (j - 48) + 47;  tab = rpw; }
    const float* rp = tab + (size_t)ridx * HD;
    const float* qp = &qlds[q * 68];
    float s1 = 0.f;
#pragma unroll 4
    for (int d = 0; d < 64; d += 4) {
      f32x4 a = *(const f32x4*)(qp + d);
      f32x4 bv = *(const f32x4*)(rp + d);
      s1 += a[0]*bv[0] + a[1]*bv[1] + a[2]*bv[2] + a[3]*bv[3];
    }
    if (j < 48) Bh[q * 49 + col] = __float2half_rn(s1);
    else        Bw[q * 49 + col] = __float2half_rn(s1);
  }

  float m_r = -3.0e38f, l_r = 0.f;
  f32x4 oacc[4] = {};   // O[q = 4g+r][d = ql + 16*dt]
  const int q64b = wq * 16 + ql;

  for (int kt = 0; kt < 36; kt++) {
    __syncthreads();   // prev tile's frag reads done (first iter: bias visible)
    *(uint4*)(KhiL + srow * 72 + sch * 8) = rkh;
    *(uint4*)(KloL + srow * 72 + sch * 8) = rkl;
    *(uint4*)(VhL  + srow * 72 + sch * 8) = rvh;
    *(uint4*)(VlL  + srow * 72 + sch * 8) = rvl;
    __syncthreads();
    if (kt < 35) {     // T14: issue next-tile loads; land under MFMA phase
      size_t tb = tbK + (size_t)(kt + 1) * 4096;
      rkh = *(const uint4*)(khi + tb + soff);
      rkl = *(const uint4*)(klo + tb + soff);
      rvh = *(const uint4*)(vhi + tb + soff);
      rvl = *(const uint4*)(vlo + tb + soff);
    }

    // ---- QK^T (swapped): S^T[key][q]; A-frag = one b128 (permuted image)
    f32x4 sacc[2] = {};
#pragma unroll
    for (int ds = 0; ds < 2; ds++) {
#pragma unroll
      for (int t2 = 0; t2 < 2; t2++) {
        int row = (hh * 2 + t2) * 16 + ql;
        s16x8 af = *(const s16x8*)(KhiL + row * 72 + ds * 32 + g * 8);
        s16x8 al = *(const s16x8*)(KloL + row * 72 + ds * 32 + g * 8);
        sacc[t2] = __builtin_amdgcn_mfma_f32_16x16x32_bf16(af, qfh[ds], sacc[t2], 0, 0, 0);
        sacc[t2] = __builtin_amdgcn_mfma_f32_16x16x32_bf16(af, qfl[ds], sacc[t2], 0, 0, 0);
        sacc[t2] = __builtin_amdgcn_mfma_f32_16x16x32_bf16(al, qfh[ds], sacc[t2], 0, 0, 0);
      }
    }

    // ---- bias + online softmax (lane owns q-row q64b; 8 keys in-lane)
    float lg[8];
    float tmax = -3.0e38f;
#pragma unroll
    for (int t2 = 0; t2 < 2; t2++)
#pragma unroll
      for (int r = 0; r < 4; r++) {
        u32 kg = (u32)(kt * 64 + hh * 32 + t2 * 16 + g * 4 + r);
        u32 kh = kg / 48u;
        u32 kw = kg - kh * 48u;
        float x = sacc[t2][r] * 0.125f
                + __half2float(Bh[q64b * 49 + (int)kh])
                + __half2float(Bw[q64b * 49 + (int)kw]);
        lg[t2 * 4 + r] = x;
        tmax = fmaxf(tmax, x);
      }
    tmax = fmaxf(tmax, __shfl_xor(tmax, 16));
    tmax = fmaxf(tmax, __shfl_xor(tmax, 32));
    if (__any(tmax > m_r + 6.0f)) {   // T13 defer-max
      float mnew = fmaxf(m_r, tmax);
      float corr = __expf(m_r - mnew);
      l_r *= corr;
      m_r = mnew;
      float cq[4];
#pragma unroll
      for (int r = 0; r < 4; r++) cq[r] = __shfl(corr, g * 4 + r);
#pragma unroll
      for (int dt = 0; dt < 4; dt++)
#pragma unroll
        for (int r = 0; r < 4; r++) oacc[dt][r] *= cq[r];
    }
    float psum = 0.f;
    s16x8 pfh, pfl;
#pragma unroll
    for (int j = 0; j < 8; j++) {
      float p = __expf(lg[j] - m_r);
      psum += p;
      u16 hi = f2bf(p);
      pfh[j] = (short)hi;
      pfl[j] = (short)f2bf(p - bf2f(hi));
    }
    psum += __shfl_xor(psum, 16);
    psum += __shfl_xor(psum, 32);
    l_r += psum;

    // ---- PV: B-frag = one b128 from permuted V^T image
#pragma unroll
    for (int dt = 0; dt < 4; dt++) {
      int row = ql + 16 * dt;
      s16x8 bhf = *(const s16x8*)(VhL + row * 72 + hh * 32 + g * 8);
      s16x8 blf = *(const s16x8*)(VlL + row * 72 + hh * 32 + g * 8);
      oacc[dt] = __builtin_amdgcn_mfma_f32_16x16x32_bf16(pfh, bhf, oacc[dt], 0, 0, 0);
      oacc[dt] = __builtin_amdgcn_mfma_f32_16x16x32_bf16(pfh, blf, oacc[dt], 0, 0, 0);
      oacc[dt] = __builtin_amdgcn_mfma_f32_16x16x32_bf16(pfl, bhf, oacc[dt], 0, 0, 0);
    }
  }

  // ---- merge the two key-streams per q-group, write out
  __syncthreads();
  if (hh == 1) {
    if (g == 0) { m_s[wq * 16 + ql] = m_r; l_s[wq * 16 + ql] = l_r; }
#pragma unroll
    for (int dt = 0; dt < 4; dt++)
#pragma unroll
      for (int r = 0; r < 4; r++)
        o_s[(wq * 16 + g * 4 + r) * 68 + ql + 16 * dt] = oacc[dt][r];
  }
  __syncthreads();
  if (hh == 0) {
    float m2 = m_s[wq * 16 + ql];
    float l2 = l_s[wq * 16 + ql];
    float mf = fmaxf(m_r, m2);
    float c1 = __expf(m_r - mf);
    float c2 = __expf(m2 - mf);
    float lf = l_r * c1 + l2 * c2;
    float c1q[4], c2q[4], lfq[4];
#pragma unroll
    for (int r = 0; r < 4; r++) {
      c1q[r] = __shfl(c1, g * 4 + r);
      c2q[r] = __shfl(c2, g * 4 + r);
      lfq[r] = __shfl(lf, g * 4 + r);
    }
    const int b = bh / 12, head = bh - (bh / 12) * 12;
#pragma unroll
    for (int dt = 0; dt < 4; dt++)
#pragma unroll
      for (int r = 0; r < 4; r++) {
        float oo = oacc[dt][r] * c1q[r]
                 + o_s[(wq * 16 + g * 4 + r) * 68 + ql + 16 * dt] * c2q[r];
        int s = s0 + wq * 16 + g * 4 + r;
        ao[((size_t)b * SEQ + s) * 768 + head * 64 + ql + 16 * dt] = oo / lfq[r];
      }
  }
}

// ---------------- proj GEMM: [4608x768] @ [768x768] + bias -> out
__global__ __launch_bounds__(256) void proj_gemm_k(
    const float* __restrict__ a, const float* __restrict__ w,
    const float* __restrict__ bias, float* __restrict__ out)
{
  __shared__ float As[16][68];
  __shared__ float Bs[16][68];
  const int tid = threadIdx.x;
  const int tn = tid & 15, tm = tid >> 4;
  const int c0 = blockIdx.x * 64;
  const int r0 = blockIdx.y * 64;
  const int arow = tid >> 2, ak4 = (tid & 3) * 4;
  const int brow = tid >> 4, bc4 = (tid & 15) * 4;
  float acc[4][4] = {};
  const float* ap = a + (size_t)(r0 + arow) * 768 + ak4;
  const float* bp = w + (size_t)brow * 768 + c0 + bc4;
  for (int k0 = 0; k0 < 768; k0 += 16) {
    F4 a4, b4;
    a4.v = *(const float4*)(ap + k0);
    b4.v = *(const float4*)(bp + (size_t)k0 * 768);
    __syncthreads();
    As[ak4+0][arow] = a4.f[0];
    As[ak4+1][arow] = a4.f[1];
    As[ak4+2][arow] = a4.f[2];
    As[ak4+3][arow] = a4.f[3];
    *(float4*)&Bs[brow][bc4] = b4.v;
    __syncthreads();
#pragma unroll
    for (int p = 0; p < 16; p++) {
      F4 av, bv;
      av.v = *(float4*)&As[p][tm*4];
      bv.v = *(float4*)&Bs[p][tn*4];
#pragma unroll
      for (int i = 0; i < 4; i++)
#pragma unroll
        for (int j = 0; j < 4; j++)
          acc[i][j] += av.f[i] * bv.f[j];
    }
  }
  float bb[4];
#pragma unroll
  for (int j = 0; j < 4; j++) bb[j] = bias[c0 + tn*4 + j];
#pragma unroll
  for (int i = 0; i < 4; i++) {
    int row = r0 + tm*4 + i;
    F4 ov;
#pragma unroll
    for (int j = 0; j < 4; j++) ov.f[j] = acc[i][j] + bb[j];
    *(float4*)(out + (size_t)row * 768 + c0 + tn*4) = ov.v;
  }
}

extern "C" void kernel_launch(void* const* d_in, const int* in_sizes, int n_in,
                              void* d_out, int out_size, void* d_ws, size_t ws_size,
                              hipStream_t stream) {
  const float* x      = (const float*)d_in[0];
  const float* qkv_w  = (const float*)d_in[1];
  const float* qkv_b  = (const float*)d_in[2];
  const float* proj_w = (const float*)d_in[3];
  const float* proj_b = (const float*)d_in[4];
  const float* rph    = (const float*)d_in[5];
  const float* rpw    = (const float*)d_in[6];
  float* out = (float*)d_out;
  float* ws  = (float*)d_ws;

  const size_t SZ = (size_t)24 * SEQ * HD;   // 3,538,944 elems
  float* qbuf = ws;                          // SZ f32
  u16* khi = (u16*)(ws + SZ);                // 4 x SZ u16
  u16* klo = khi + SZ;
  u16* vhi = klo + SZ;
  u16* vlo = vhi + SZ;
  float* ao = ws + 3 * SZ;                   // SZ f32

  qkv_gemm_k<<<dim3(36, 72), 256, 0, stream>>>(x, qkv_w, qkv_b, qbuf, khi, klo, vhi, vlo);
  attn_k    <<<dim3(36, 24), 512, 0, stream>>>(qbuf, khi, klo, vhi, vlo, rph, rpw, ao);
  proj_gemm_k<<<dim3(12, 72), 256, 0, stream>>>(ao, proj_w, proj_b, out);
}

// Round 4
// 522.131 us; speedup vs baseline: 3.7283x; 1.2683x over previous
//
#include <hip/hip_runtime.h>
#include <hip/hip_fp16.h>

#define HD 64
#define SEQ 2304

typedef unsigned short u16;
typedef unsigned int u32;
using f32x4 = __attribute__((ext_vector_type(4))) float;
using s16x8 = __attribute__((ext_vector_type(8))) short;

static __device__ __forceinline__ u16 f2bf(float x) {
  union { float f; u32 u; } a; a.f = x;
  u32 r = a.u + 0x7fffu + ((a.u >> 16) & 1u);
  return (u16)(r >> 16);
}
static __device__ __forceinline__ float bf2f(u16 h) {
  union { float f; u32 u; } a; a.u = ((u32)h) << 16; return a.f;
}

// ---------------- convert + transpose weights: w[K][N] f32 -> wT[N][K] bf16 hi/lo
__global__ __launch_bounds__(256) void conv_wT_k(
    const float* __restrict__ src, u16* __restrict__ dhi, u16* __restrict__ dlo,
    int K, int N)
{
  __shared__ u32 t[64][65];
  const int tid = threadIdx.x;
  const int n0 = blockIdx.x * 64, k0 = blockIdx.y * 64;
  const int r = tid >> 2, c0 = (tid & 3) * 16;
  const float* sp = src + (size_t)(k0 + r) * N + n0 + c0;
#pragma unroll
  for (int j = 0; j < 16; j += 4) {
    f32x4 v = *(const f32x4*)(sp + j);
#pragma unroll
    for (int e = 0; e < 4; e++) {
      float x = v[e];
      u16 h = f2bf(x);
      u16 l = f2bf(x - bf2f(h));
      t[r][c0 + j + e] = (u32)h | ((u32)l << 16);
    }
  }
  __syncthreads();
  u16 hb[16], lb[16];
#pragma unroll
  for (int j = 0; j < 16; j++) {
    u32 p = t[c0 + j][r];
    hb[j] = (u16)(p & 0xffffu);
    lb[j] = (u16)(p >> 16);
  }
  size_t off = (size_t)(n0 + r) * K + k0 + c0;
  *(uint4*)(dhi + off)     = *(uint4*)&hb[0];
  *(uint4*)(dhi + off + 8) = *(uint4*)&hb[8];
  *(uint4*)(dlo + off)     = *(uint4*)&lb[0];
  *(uint4*)(dlo + off + 8) = *(uint4*)&lb[8];
}

// ---------------- QKV GEMM via split-bf16 MFMA: x[4608x768] @ wT -> q fp32 + K/V images
__global__ __launch_bounds__(256) void qkv_mfma_k(
    const float* __restrict__ x, const u16* __restrict__ bthi, const u16* __restrict__ btlo,
    const float* __restrict__ bias,
    float* __restrict__ qbuf, u16* __restrict__ khi, u16* __restrict__ klo,
    u16* __restrict__ vhi, u16* __restrict__ vlo)
{
  __shared__ __align__(16) u16 Ah[128*40], Al[128*40], Bh2[128*40], Bl2[128*40];
  const int tid = threadIdx.x;
  const int lane = tid & 63, wid = tid >> 6;
  const int g = lane >> 4, ql = lane & 15;
  const int wr = wid >> 1, wc = wid & 1;
  const int c0 = blockIdx.x * 128, r0 = blockIdx.y * 128;
  const int srow = tid >> 1, half = tid & 1;

  const float* ag = x + (size_t)(r0 + srow) * 768 + half * 16;
  const u16* bgh = bthi + (size_t)(c0 + srow) * 768 + half * 16;
  const u16* bgl = btlo + (size_t)(c0 + srow) * 768 + half * 16;

  f32x4 pa[4]; uint4 pbh[2], pbl[2];
#pragma unroll
  for (int j = 0; j < 4; j++) pa[j] = *(const f32x4*)(ag + j * 4);
  pbh[0] = *(const uint4*)bgh; pbh[1] = *(const uint4*)(bgh + 8);
  pbl[0] = *(const uint4*)bgl; pbl[1] = *(const uint4*)(bgl + 8);

  f32x4 acc[4][4] = {};

  for (int ks = 0; ks < 24; ks++) {
    __syncthreads();
    {
      u16 hb[16], lb[16];
#pragma unroll
      for (int j = 0; j < 16; j++) {
        float xv = pa[j >> 2][j & 3];
        u16 h = f2bf(xv);
        hb[j] = h; lb[j] = f2bf(xv - bf2f(h));
      }
      u16* d1 = Ah + srow * 40 + half * 16;
      u16* d2 = Al + srow * 40 + half * 16;
      *(uint4*)d1 = *(uint4*)&hb[0];
      *(uint4*)(d1 + 8) = *(uint4*)&hb[8];
      *(uint4*)d2 = *(uint4*)&lb[0];
      *(uint4*)(d2 + 8) = *(uint4*)&lb[8];
      u16* d3 = Bh2 + srow * 40 + half * 16;
      u16* d4 = Bl2 + srow * 40 + half * 16;
      *(uint4*)d3 = pbh[0]; *(uint4*)(d3 + 8) = pbh[1];
      *(uint4*)d4 = pbl[0]; *(uint4*)(d4 + 8) = pbl[1];
    }
    __syncthreads();
    if (ks < 23) {
      const float* a2 = ag + (ks + 1) * 32;
#pragma unroll
      for (int j = 0; j < 4; j++) pa[j] = *(const f32x4*)(a2 + j * 4);
      pbh[0] = *(const uint4*)(bgh + (ks + 1) * 32);
      pbh[1] = *(const uint4*)(bgh + (ks + 1) * 32 + 8);
      pbl[0] = *(const uint4*)(bgl + (ks + 1) * 32);
      pbl[1] = *(const uint4*)(bgl + (ks + 1) * 32 + 8);
    }
    s16x8 bfh[4], bfl[4];
#pragma unroll
    for (int nt = 0; nt < 4; nt++) {
      bfh[nt] = *(const s16x8*)(Bh2 + (wc * 64 + nt * 16 + ql) * 40 + g * 8);
      bfl[nt] = *(const s16x8*)(Bl2 + (wc * 64 + nt * 16 + ql) * 40 + g * 8);
    }
#pragma unroll
    for (int mt = 0; mt < 4; mt++) {
      s16x8 ah = *(const s16x8*)(Ah + (wr * 64 + mt * 16 + ql) * 40 + g * 8);
      s16x8 al = *(const s16x8*)(Al + (wr * 64 + mt * 16 + ql) * 40 + g * 8);
#pragma unroll
      for (int nt = 0; nt < 4; nt++) {
        acc[mt][nt] = __builtin_amdgcn_mfma_f32_16x16x32_bf16(ah, bfh[nt], acc[mt][nt], 0, 0, 0);
        acc[mt][nt] = __builtin_amdgcn_mfma_f32_16x16x32_bf16(ah, bfl[nt], acc[mt][nt], 0, 0, 0);
        acc[mt][nt] = __builtin_amdgcn_mfma_f32_16x16x32_bf16(al, bfh[nt], acc[mt][nt], 0, 0, 0);
      }
    }
  }
  // ---- epilogue: scatter to q fp32 / K,V permuted tile-images
  const int col0 = c0 + wc * 64;
  const int row0 = r0 + wr * 64;
  const int hb36 = col0 >> 6;
  const int which = hb36 / 12, head = hb36 - (hb36 / 12) * 12;
  const int b = row0 / 2304;
  const int sb = row0 - b * 2304;
  const int bh = b * 12 + head;
  float bb[4];
#pragma unroll
  for (int nt = 0; nt < 4; nt++) bb[nt] = bias[col0 + nt * 16 + ql];
  if (which == 0) {
#pragma unroll
    for (int mt = 0; mt < 4; mt++)
#pragma unroll
      for (int nt = 0; nt < 4; nt++)
#pragma unroll
        for (int r = 0; r < 4; r++) {
          int s = sb + mt * 16 + g * 4 + r;
          qbuf[((size_t)bh * SEQ + s) * 64 + nt * 16 + ql] = acc[mt][nt][r] + bb[nt];
        }
  } else {
    const int kt = sb >> 6;
    const size_t tile = ((size_t)bh * 36 + kt) * 4096;
    if (which == 1) {
#pragma unroll
      for (int mt = 0; mt < 4; mt++)
#pragma unroll
        for (int nt = 0; nt < 4; nt++) {
          int pc = (nt >> 1) * 32 + (ql >> 2) * 8 + (nt & 1) * 4 + (ql & 3);
#pragma unroll
          for (int r = 0; r < 4; r++) {
            int key = mt * 16 + g * 4 + r;
            float xv = acc[mt][nt][r] + bb[nt];
            u16 h = f2bf(xv);
            khi[tile + key * 64 + pc] = h;
            klo[tile + key * 64 + pc] = f2bf(xv - bf2f(h));
          }
        }
    } else {
#pragma unroll
      for (int mt = 0; mt < 4; mt++)
#pragma unroll
        for (int nt = 0; nt < 4; nt++)
#pragma unroll
          for (int r = 0; r < 4; r++) {
            int d = nt * 16 + ql;
            int vc = (mt >> 1) * 32 + g * 8 + (mt & 1) * 4 + r;
            float xv = acc[mt][nt][r] + bb[nt];
            u16 h = f2bf(xv);
            vhi[tile + d * 64 + vc] = h;
            vlo[tile + d * 64 + vc] = f2bf(xv - bf2f(h));
          }
    }
  }
}

// ---------------- Fused attention: split-bf16 MFMA, swapped QK^T, online softmax
__global__ __launch_bounds__(512) void attn_k(
    const float* __restrict__ qb,
    const u16* __restrict__ khi, const u16* __restrict__ klo,
    const u16* __restrict__ vhi, const u16* __restrict__ vlo,
    const float* __restrict__ rph, const float* __restrict__ rpw,
    float* __restrict__ ao)
{
  __shared__ __align__(16) char pool[49664];
  u16* KhiL = (u16*)pool;              // [64 key][72]
  u16* KloL = (u16*)(pool + 9216);
  u16* VhL  = (u16*)(pool + 18432);    // [64 d][72]
  u16* VlL  = (u16*)(pool + 27648);
  __half* Bh = (__half*)(pool + 36864);   // [48 kh][64 q]  (transposed: conflict-free reads)
  __half* Bw = (__half*)(pool + 43008);   // [48 kw][64 q]
  float* m_s = (float*)(pool + 49152);    // [64]
  float* l_s = (float*)(pool + 49408);    // [64]
  float* qlds = (float*)pool;             // prologue alias [64][68] f32
  float* o_s  = (float*)pool;             // epilogue alias [64][68] f32

  const int tid  = threadIdx.x;
  const int lane = tid & 63;
  const int wid  = tid >> 6;
  const int g    = lane >> 4;
  const int ql   = lane & 15;
  const int wq   = wid & 3;     // q-group: rows [16*wq, 16*wq+16)
  const int hh   = wid >> 2;    // key-half stream
  const int qt   = blockIdx.x;  // 36
  const int bh   = blockIdx.y;  // 24
  const int s0   = qt * 64;

  // ---- stage Q tile fp32 -> LDS
  {
    int row = tid >> 3, c0 = (tid & 7) * 8;
    const float* src = qb + ((size_t)bh * SEQ + s0 + row) * HD + c0;
    f32x4 v0 = *(const f32x4*)src;
    f32x4 v1 = *(const f32x4*)(src + 4);
    *(f32x4*)&qlds[row * 68 + c0]     = v0;
    *(f32x4*)&qlds[row * 68 + c0 + 4] = v1;
  }
  __syncthreads();

  // ---- Q fragments hi/lo (lane's q = 16*wq + ql)
  s16x8 qfh[2], qfl[2];
  {
    int qrow = wq * 16 + ql;
#pragma unroll
    for (int ds = 0; ds < 2; ds++) {
#pragma unroll
      for (int h2 = 0; h2 < 2; h2++) {
        f32x4 qv = *(const f32x4*)&qlds[qrow * 68 + g * 4 + h2 * 16 + ds * 32];
#pragma unroll
        for (int j = 0; j < 4; j++) {
          float xx = qv[j];
          u16 hi = f2bf(xx);
          u16 lo = f2bf(xx - bf2f(hi));
          qfh[ds][h2 * 4 + j] = (short)hi;
          qfl[ds][h2 * 4 + j] = (short)lo;
        }
      }
    }
  }

  // ---- prefetch tile 0; staging chunk-permutation kills write bank conflicts
  const size_t tbK = (size_t)bh * 36 * 4096;
  const int srow = tid >> 3;
  const int sch  = ((tid & 7) - (srow & 7)) & 7;
  const size_t soff = (size_t)srow * 64 + sch * 8;
  uint4 rkh = *(const uint4*)(khi + tbK + soff);
  uint4 rkl = *(const uint4*)(klo + tbK + soff);
  uint4 rvh = *(const uint4*)(vhi + tbK + soff);
  uint4 rvl = *(const uint4*)(vlo + tbK + soff);

  // ---- decomposed rel-pos bias tables (fp16, transposed layout)
  for (int i = tid; i < 64 * 96; i += 512) {
    int q = i / 96, j = i - (i / 96) * 96;
    int s = s0 + q;
    int qhg = s / 48, qw = s - qhg * 48;
    const float* tab;
    int ridx, col;
    if (j < 48) { col = j;      ridx = qhg - j + 47;        tab = rph; }
    else        { col = j - 48; ridx = qw - (j - 48) + 47;  tab = rpw; }
    const float* rp = tab + (size_t)ridx * HD;
    const float* qp = &qlds[q * 68];
    float s1 = 0.f;
#pragma unroll 4
    for (int d = 0; d < 64; d += 4) {
      f32x4 a = *(const f32x4*)(qp + d);
      f32x4 bv = *(const f32x4*)(rp + d);
      s1 += a[0]*bv[0] + a[1]*bv[1] + a[2]*bv[2] + a[3]*bv[3];
    }
    if (j < 48) Bh[col * 64 + q] = __float2half_rn(s1);
    else        Bw[col * 64 + q] = __float2half_rn(s1);
  }

  float m_r = -3.0e38f, l_r = 0.f;
  f32x4 oacc[4] = {};   // O[q = 4g+r][d = ql + 16*dt]
  const int q64b = wq * 16 + ql;

  for (int kt = 0; kt < 36; kt++) {
    __syncthreads();   // prev tile's frag reads done (first iter: bias/qlds done)
    *(uint4*)(KhiL + srow * 72 + sch * 8) = rkh;
    *(uint4*)(KloL + srow * 72 + sch * 8) = rkl;
    *(uint4*)(VhL  + srow * 72 + sch * 8) = rvh;
    *(uint4*)(VlL  + srow * 72 + sch * 8) = rvl;
    __syncthreads();
    if (kt < 35) {     // T14: issue next-tile loads; land under MFMA phase
      size_t tb = tbK + (size_t)(kt + 1) * 4096;
      rkh = *(const uint4*)(khi + tb + soff);
      rkl = *(const uint4*)(klo + tb + soff);
      rvh = *(const uint4*)(vhi + tb + soff);
      rvl = *(const uint4*)(vlo + tb + soff);
    }

    // ---- QK^T (swapped): S^T[key][q]; A-frag = one b128 (permuted image)
    f32x4 sacc[2] = {};
#pragma unroll
    for (int ds = 0; ds < 2; ds++) {
#pragma unroll
      for (int t2 = 0; t2 < 2; t2++) {
        int row = (hh * 2 + t2) * 16 + ql;
        s16x8 af = *(const s16x8*)(KhiL + row * 72 + ds * 32 + g * 8);
        s16x8 al = *(const s16x8*)(KloL + row * 72 + ds * 32 + g * 8);
        sacc[t2] = __builtin_amdgcn_mfma_f32_16x16x32_bf16(af, qfh[ds], sacc[t2], 0, 0, 0);
        sacc[t2] = __builtin_amdgcn_mfma_f32_16x16x32_bf16(af, qfl[ds], sacc[t2], 0, 0, 0);
        sacc[t2] = __builtin_amdgcn_mfma_f32_16x16x32_bf16(al, qfh[ds], sacc[t2], 0, 0, 0);
      }
    }

    // ---- bias + online softmax (lane owns q-row q64b; 8 keys in-lane)
    float lg[8];
    float tmax = -3.0e38f;
#pragma unroll
    for (int t2 = 0; t2 < 2; t2++)
#pragma unroll
      for (int r = 0; r < 4; r++) {
        u32 kg = (u32)(kt * 64 + hh * 32 + t2 * 16 + g * 4 + r);
        u32 kh = kg / 48u;
        u32 kw = kg - kh * 48u;
        float x = sacc[t2][r] * 0.125f
                + __half2float(Bh[(int)kh * 64 + q64b])
                + __half2float(Bw[(int)kw * 64 + q64b]);
        lg[t2 * 4 + r] = x;
        tmax = fmaxf(tmax, x);
      }
    tmax = fmaxf(tmax, __shfl_xor(tmax, 16));
    tmax = fmaxf(tmax, __shfl_xor(tmax, 32));
    if (__any(tmax > m_r + 6.0f)) {   // T13 defer-max
      float mnew = fmaxf(m_r, tmax);
      float corr = __expf(m_r - mnew);
      l_r *= corr;
      m_r = mnew;
      float cq[4];
#pragma unroll
      for (int r = 0; r < 4; r++) cq[r] = __shfl(corr, g * 4 + r);
#pragma unroll
      for (int dt = 0; dt < 4; dt++)
#pragma unroll
        for (int r = 0; r < 4; r++) oacc[dt][r] *= cq[r];
    }
    float psum = 0.f;
    s16x8 pfh, pfl;
#pragma unroll
    for (int j = 0; j < 8; j++) {
      float p = __expf(lg[j] - m_r);
      psum += p;
      u16 hi = f2bf(p);
      pfh[j] = (short)hi;
      pfl[j] = (short)f2bf(p - bf2f(hi));
    }
    psum += __shfl_xor(psum, 16);
    psum += __shfl_xor(psum, 32);
    l_r += psum;

    // ---- PV: B-frag = one b128 from permuted V^T image
#pragma unroll
    for (int dt = 0; dt < 4; dt++) {
      int row = ql + 16 * dt;
      s16x8 bhf = *(const s16x8*)(VhL + row * 72 + hh * 32 + g * 8);
      s16x8 blf = *(const s16x8*)(VlL + row * 72 + hh * 32 + g * 8);
      oacc[dt] = __builtin_amdgcn_mfma_f32_16x16x32_bf16(pfh, bhf, oacc[dt], 0, 0, 0);
      oacc[dt] = __builtin_amdgcn_mfma_f32_16x16x32_bf16(pfh, blf, oacc[dt], 0, 0, 0);
      oacc[dt] = __builtin_amdgcn_mfma_f32_16x16x32_bf16(pfl, bhf, oacc[dt], 0, 0, 0);
    }
  }

  // ---- merge the two key-streams per q-group, write out
  __syncthreads();
  if (hh == 1) {
    if (g == 0) { m_s[wq * 16 + ql] = m_r; l_s[wq * 16 + ql] = l_r; }
#pragma unroll
    for (int dt = 0; dt < 4; dt++)
#pragma unroll
      for (int r = 0; r < 4; r++)
        o_s[(wq * 16 + g * 4 + r) * 68 + ql + 16 * dt] = oacc[dt][r];
  }
  __syncthreads();
  if (hh == 0) {
    float m2 = m_s[wq * 16 + ql];
    float l2 = l_s[wq * 16 + ql];
    float mf = fmaxf(m_r, m2);
    float c1 = __expf(m_r - mf);
    float c2 = __expf(m2 - mf);
    float lf = l_r * c1 + l2 * c2;
    float c1q[4], c2q[4], lfq[4];
#pragma unroll
    for (int r = 0; r < 4; r++) {
      c1q[r] = __shfl(c1, g * 4 + r);
      c2q[r] = __shfl(c2, g * 4 + r);
      lfq[r] = __shfl(lf, g * 4 + r);
    }
    const int b = bh / 12, head = bh - (bh / 12) * 12;
#pragma unroll
    for (int dt = 0; dt < 4; dt++)
#pragma unroll
      for (int r = 0; r < 4; r++) {
        float oo = oacc[dt][r] * c1q[r]
                 + o_s[(wq * 16 + g * 4 + r) * 68 + ql + 16 * dt] * c2q[r];
        int s = s0 + wq * 16 + g * 4 + r;
        ao[((size_t)b * SEQ + s) * 768 + head * 64 + ql + 16 * dt] = oo / lfq[r];
      }
  }
}

// ---------------- proj GEMM via split-bf16 MFMA: ao[4608x768] @ wpT + bias -> out
__global__ __launch_bounds__(256) void proj_mfma_k(
    const float* __restrict__ a, const u16* __restrict__ bthi, const u16* __restrict__ btlo,
    const float* __restrict__ bias, float* __restrict__ out)
{
  __shared__ __align__(16) u16 Ah[128*40], Al[128*40], Bh2[128*40], Bl2[128*40];
  const int tid = threadIdx.x;
  const int lane = tid & 63, wid = tid >> 6;
  const int g = lane >> 4, ql = lane & 15;
  const int wr = wid >> 1, wc = wid & 1;
  const int c0 = blockIdx.x * 128, r0 = blockIdx.y * 128;
  const int srow = tid >> 1, half = tid & 1;

  const float* ag = a + (size_t)(r0 + srow) * 768 + half * 16;
  const u16* bgh = bthi + (size_t)(c0 + srow) * 768 + half * 16;
  const u16* bgl = btlo + (size_t)(c0 + srow) * 768 + half * 16;

  f32x4 pa[4]; uint4 pbh[2], pbl[2];
#pragma unroll
  for (int j = 0; j < 4; j++) pa[j] = *(const f32x4*)(ag + j * 4);
  pbh[0] = *(const uint4*)bgh; pbh[1] = *(const uint4*)(bgh + 8);
  pbl[0] = *(const uint4*)bgl; pbl[1] = *(const uint4*)(bgl + 8);

  f32x4 acc[4][4] = {};

  for (int ks = 0; ks < 24; ks++) {
    __syncthreads();
    {
      u16 hb[16], lb[16];
#pragma unroll
      for (int j = 0; j < 16; j++) {
        float xv = pa[j >> 2][j & 3];
        u16 h = f2bf(xv);
        hb[j] = h; lb[j] = f2bf(xv - bf2f(h));
      }
      u16* d1 = Ah + srow * 40 + half * 16;
      u16* d2 = Al + srow * 40 + half * 16;
      *(uint4*)d1 = *(uint4*)&hb[0];
      *(uint4*)(d1 + 8) = *(uint4*)&hb[8];
      *(uint4*)d2 = *(uint4*)&lb[0];
      *(uint4*)(d2 + 8) = *(uint4*)&lb[8];
      u16* d3 = Bh2 + srow * 40 + half * 16;
      u16* d4 = Bl2 + srow * 40 + half * 16;
      *(uint4*)d3 = pbh[0]; *(uint4*)(d3 + 8) = pbh[1];
      *(uint4*)d4 = pbl[0]; *(uint4*)(d4 + 8) = pbl[1];
    }
    __syncthreads();
    if (ks < 23) {
      const float* a2 = ag + (ks + 1) * 32;
#pragma unroll
      for (int j = 0; j < 4; j++) pa[j] = *(const f32x4*)(a2 + j * 4);
      pbh[0] = *(const uint4*)(bgh + (ks + 1) * 32);
      pbh[1] = *(const uint4*)(bgh + (ks + 1) * 32 + 8);
      pbl[0] = *(const uint4*)(bgl + (ks + 1) * 32);
      pbl[1] = *(const uint4*)(bgl + (ks + 1) * 32 + 8);
    }
    s16x8 bfh[4], bfl[4];
#pragma unroll
    for (int nt = 0; nt < 4; nt++) {
      bfh[nt] = *(const s16x8*)(Bh2 + (wc * 64 + nt * 16 + ql) * 40 + g * 8);
      bfl[nt] = *(const s16x8*)(Bl2 + (wc * 64 + nt * 16 + ql) * 40 + g * 8);
    }
#pragma unroll
    for (int mt = 0; mt < 4; mt++) {
      s16x8 ah = *(const s16x8*)(Ah + (wr * 64 + mt * 16 + ql) * 40 + g * 8);
      s16x8 al = *(const s16x8*)(Al + (wr * 64 + mt * 16 + ql) * 40 + g * 8);
#pragma unroll
      for (int nt = 0; nt < 4; nt++) {
        acc[mt][nt] = __builtin_amdgcn_mfma_f32_16x16x32_bf16(ah, bfh[nt], acc[mt][nt], 0, 0, 0);
        acc[mt][nt] = __builtin_amdgcn_mfma_f32_16x16x32_bf16(ah, bfl[nt], acc[mt][nt], 0, 0, 0);
        acc[mt][nt] = __builtin_amdgcn_mfma_f32_16x16x32_bf16(al, bfh[nt], acc[mt][nt], 0, 0, 0);
      }
    }
  }
  const int col0 = c0 + wc * 64;
  const int row0 = r0 + wr * 64;
  float bb[4];
#pragma unroll
  for (int nt = 0; nt < 4; nt++) bb[nt] = bias[col0 + nt * 16 + ql];
#pragma unroll
  for (int mt = 0; mt < 4; mt++)
#pragma unroll
    for (int nt = 0; nt < 4; nt++)
#pragma unroll
      for (int r = 0; r < 4; r++)
        out[(size_t)(row0 + mt * 16 + g * 4 + r) * 768 + col0 + nt * 16 + ql] =
            acc[mt][nt][r] + bb[nt];
}

extern "C" void kernel_launch(void* const* d_in, const int* in_sizes, int n_in,
                              void* d_out, int out_size, void* d_ws, size_t ws_size,
                              hipStream_t stream) {
  const float* x      = (const float*)d_in[0];
  const float* qkv_w  = (const float*)d_in[1];
  const float* qkv_b  = (const float*)d_in[2];
  const float* proj_w = (const float*)d_in[3];
  const float* proj_b = (const float*)d_in[4];
  const float* rph    = (const float*)d_in[5];
  const float* rpw    = (const float*)d_in[6];
  float* out = (float*)d_out;
  float* ws  = (float*)d_ws;

  const size_t SZ = (size_t)24 * SEQ * HD;   // 3,538,944 elems
  float* qbuf = ws;                          // SZ f32
  u16* khi = (u16*)(ws + SZ);                // 4 x SZ u16
  u16* klo = khi + SZ;
  u16* vhi = klo + SZ;
  u16* vlo = vhi + SZ;
  float* ao = ws + 3 * SZ;                   // SZ f32
  u16* wqThi = (u16*)(ws + 4 * SZ);          // 768*2304
  u16* wqTlo = wqThi + 768 * 2304;
  u16* wpThi = wqTlo + 768 * 2304;           // 768*768
  u16* wpTlo = wpThi + 768 * 768;

  conv_wT_k <<<dim3(36, 12), 256, 0, stream>>>(qkv_w, wqThi, wqTlo, 768, 2304);
  conv_wT_k <<<dim3(12, 12), 256, 0, stream>>>(proj_w, wpThi, wpTlo, 768, 768);
  qkv_mfma_k<<<dim3(18, 36), 256, 0, stream>>>(x, wqThi, wqTlo, qkv_b,
                                               qbuf, khi, klo, vhi, vlo);
  attn_k    <<<dim3(36, 24), 512, 0, stream>>>(qbuf, khi, klo, vhi, vlo, rph, rpw, ao);
  proj_mfma_k<<<dim3(6, 36), 256, 0, stream>>>(ao, wpThi, wpTlo, proj_b, out);
}